// Round 8
// baseline (194.066 us; speedup 1.0000x reference)
//
#include <hip/hip_runtime.h>
#include <hip/hip_bf16.h>

static constexpr float SLOPE = 0.01f;   // leaky_relu negative_slope
static constexpr float EPSN  = 1e-12f;  // F.normalize eps

typedef float f32x4 __attribute__((ext_vector_type(4)));
typedef short short8 __attribute__((ext_vector_type(8)));

#define KPAD 512     // in_dim = 500 padded to 16 k-tiles of 32
#define CAP  16      // edges per node cached in LDS for routing iters 2,3
#define XSTRIDE 132  // LDS row stride in floats (128 + 4 pad)

// VALU (DPP) butterfly/rotate add: x + dpp(x). No DS-pipe traffic.
// quad_perm[1,0,3,2]=0xB1 (xor1), quad_perm[2,3,0,1]=0x4E (xor2),
// row_ror:4=0x124, row_ror:8=0x128 (rotate within 16-lane row).
template <int CTRL>
__device__ __forceinline__ float dpp_add(float x) {
  const int y = __builtin_amdgcn_mov_dpp(__builtin_bit_cast(int, x), CTRL, 0xF, 0xF, true);
  return x + __builtin_bit_cast(float, y);
}

// round-to-nearest bf16 split: v ~= hi + lo, each exactly representable in bf16
__device__ __forceinline__ void bf16_split(float v, short& hi, short& lo) {
  __hip_bfloat16 h = __float2bfloat16(v);
  float hf = __bfloat162float(h);
  __hip_bfloat16 l = __float2bfloat16(v - hf);
  hi = __builtin_bit_cast(short, h);
  lo = __builtin_bit_cast(short, l);
}

// ---------------------------------------------------------------------------
// One-time W prep: split to bf16 hi/lo, swizzle to w2[kt][kc][col][8], zero-pad k.
// ---------------------------------------------------------------------------
__global__ __launch_bounds__(256) void prep_w_k(const float* __restrict__ W,
                                                short* __restrict__ w2h,
                                                short* __restrict__ w2l, int in_dim) {
  const int idx = blockIdx.x * 256 + threadIdx.x;   // over KPAD*64
  if (idx >= KPAD * 64) return;
  const int k = idx >> 6, col = idx & 63;
  const float v = (k < in_dim) ? W[(size_t)k * 64 + col] : 0.0f;
  short hi, lo;
  bf16_split(v, hi, lo);
  const int kt = k >> 5, kc = (k >> 3) & 3, e = k & 7;
  const int off = (((kt * 4 + kc) * 64) + col) * 8 + e;
  w2h[off] = hi;
  w2l[off] = lo;
}

// ---------------------------------------------------------------------------
// Fused MFMA GEMM: xn = capsnorm(leaky_relu(x @ W + b)).
// 64 rows/block, 4 waves x 16 rows. x staged in 128-k chunks (33.8 KB LDS ->
// 4 blocks/CU capacity, ~12 waves/CU: the occupancy regime proven OK in r5/r6)
// with row-contiguous coalesced reads (lanes 0-31 = 512 contiguous bytes).
// Fragments via ds_read_b128 at stride 132 floats. B fragments from
// pre-swizzled w2h/w2l in global (L2-resident, contiguous 1KB per instr).
// Split-bf16: acc += Ah*Bh + Ah*Bl + Al*Bh. C/D: col=lane&15, row=(lane>>4)*4+reg.
// ---------------------------------------------------------------------------
__global__ __launch_bounds__(256) void gemm_mfma_capsnorm_k(
    const float* __restrict__ x, const short* __restrict__ w2h,
    const short* __restrict__ w2l, const float* __restrict__ b,
    float* __restrict__ xn, int n, int in_dim) {
  __shared__ __align__(16) float xs[64 * XSTRIDE];   // 33,792 B

  const int tid  = threadIdx.x;
  const int lane = tid & 63;
  const int w    = tid >> 6;
  const int l15  = lane & 15;
  const int kcL  = lane >> 4;
  const int row0 = blockIdx.x * 64;

  f32x4 acc0 = {0.f, 0.f, 0.f, 0.f};
  f32x4 acc1 = {0.f, 0.f, 0.f, 0.f};
  f32x4 acc2 = {0.f, 0.f, 0.f, 0.f};
  f32x4 acc3 = {0.f, 0.f, 0.f, 0.f};

  const float* xfrag = &xs[(w * 16 + l15) * XSTRIDE + kcL * 8];

  for (int chunk = 0; chunk < 4; ++chunk) {
    const int kbase = chunk * 128;
    // --- stage 64 rows x 128 k, coalesced (lanes 0-31: 512B contiguous) ---
#pragma unroll
    for (int i = 0; i < 8; ++i) {
      const int idx = i * 256 + tid;
      const int r = idx >> 5;          // row 0..63
      const int c = idx & 31;          // float4 chunk 0..31
      const int grow = row0 + r;
      const int k = kbase + c * 4;
      float4 v = make_float4(0.f, 0.f, 0.f, 0.f);
      if (grow < n && k + 4 <= in_dim)   // 500 % 4 == 0: chunks all-or-nothing
        v = *reinterpret_cast<const float4*>(x + (size_t)grow * in_dim + k);
      *reinterpret_cast<float4*>(&xs[r * XSTRIDE + c * 4]) = v;
    }
    __syncthreads();

    // --- 4 k-tiles of 32 per chunk ---
#pragma unroll
    for (int ktl = 0; ktl < 4; ++ktl) {
      const float4 a  = *reinterpret_cast<const float4*>(xfrag + ktl * 32);
      const float4 c4 = *reinterpret_cast<const float4*>(xfrag + ktl * 32 + 4);
      short hb[8], lb[8];
      bf16_split(a.x,  hb[0], lb[0]);
      bf16_split(a.y,  hb[1], lb[1]);
      bf16_split(a.z,  hb[2], lb[2]);
      bf16_split(a.w,  hb[3], lb[3]);
      bf16_split(c4.x, hb[4], lb[4]);
      bf16_split(c4.y, hb[5], lb[5]);
      bf16_split(c4.z, hb[6], lb[6]);
      bf16_split(c4.w, hb[7], lb[7]);
      const short8 ah = *reinterpret_cast<const short8*>(hb);
      const short8 al = *reinterpret_cast<const short8*>(lb);
      const int ktg = chunk * 4 + ktl;
      const size_t base = ((size_t)(ktg * 4 + kcL) * 64) * 8;
#pragma unroll
      for (int nt = 0; nt < 4; ++nt) {
        const short8 bh = *reinterpret_cast<const short8*>(w2h + base + (size_t)(nt * 16 + l15) * 8);
        const short8 bl = *reinterpret_cast<const short8*>(w2l + base + (size_t)(nt * 16 + l15) * 8);
        f32x4& acc = nt == 0 ? acc0 : nt == 1 ? acc1 : nt == 2 ? acc2 : acc3;
        acc = __builtin_amdgcn_mfma_f32_16x16x32_bf16(ah, bh, acc, 0, 0, 0);
        acc = __builtin_amdgcn_mfma_f32_16x16x32_bf16(ah, bl, acc, 0, 0, 0);
        acc = __builtin_amdgcn_mfma_f32_16x16x32_bf16(al, bh, acc, 0, 0, 0);
      }
    }
    __syncthreads();
  }

  // --- epilogue: bias + leaky_relu + capsnorm (capsule = 8 cols) ---
#pragma unroll
  for (int nt = 0; nt < 4; ++nt) {
    const f32x4 acc = nt == 0 ? acc0 : nt == 1 ? acc1 : nt == 2 ? acc2 : acc3;
    const float bcol = b[nt * 16 + l15];
#pragma unroll
    for (int reg = 0; reg < 4; ++reg) {
      float v = acc[reg] + bcol;
      v = v > 0.f ? v : SLOPE * v;
      float s = v * v;
      s = dpp_add<0xB1>(s);        // xor1 (VALU)
      s = dpp_add<0x4E>(s);        // xor2 (VALU)
      s += __shfl_xor(s, 4);       // xor4
      const float inv = 1.0f / fmaxf(sqrtf(s), EPSN);
      const int grow = row0 + w * 16 + ((lane >> 4) << 2) + reg;
      if (grow < n) xn[(size_t)grow * 64 + nt * 16 + l15] = v * inv;
    }
  }
}

// ---------------------------------------------------------------------------
// CSR construction: counts -> exclusive scan -> cursor scatter
// ---------------------------------------------------------------------------
__global__ __launch_bounds__(256) void zero_int_k(int* __restrict__ p, int n) {
  const int i = blockIdx.x * blockDim.x + threadIdx.x;
  if (i < n) p[i] = 0;
}

__global__ __launch_bounds__(256) void hist_k(const int* __restrict__ trg,
                                              int* __restrict__ counts, int m) {
  const int e = blockIdx.x * blockDim.x + threadIdx.x;
  if (e < m) atomicAdd(&counts[trg[e]], 1);
}

__global__ __launch_bounds__(256) void scanA_k(const int* __restrict__ counts,
                                               int* __restrict__ bsum, int n) {
  const int i = blockIdx.x * 256 + threadIdx.x;
  int v = (i < n) ? counts[i] : 0;
  v += __shfl_xor(v, 1);  v += __shfl_xor(v, 2);  v += __shfl_xor(v, 4);
  v += __shfl_xor(v, 8);  v += __shfl_xor(v, 16); v += __shfl_xor(v, 32);
  __shared__ int wsum[4];
  if ((threadIdx.x & 63) == 0) wsum[threadIdx.x >> 6] = v;
  __syncthreads();
  if (threadIdx.x == 0) bsum[blockIdx.x] = wsum[0] + wsum[1] + wsum[2] + wsum[3];
}

// PARALLEL exclusive scan of block sums (nblk <= 256)
__global__ __launch_bounds__(256) void scanB_k(int* __restrict__ bsum, int nblk,
                                               int* __restrict__ row_ptr, int n, int m) {
  const int i = threadIdx.x;
  const int lane = i & 63;
  const int wave = i >> 6;
  const int v = (i < nblk) ? bsum[i] : 0;
  int inc = v;
#pragma unroll
  for (int d = 1; d < 64; d <<= 1) {
    int t = __shfl_up(inc, d);
    if (lane >= d) inc += t;
  }
  __shared__ int wsum[4];
  if (lane == 63) wsum[wave] = inc;
  __syncthreads();
  int base = 0;
  for (int q = 0; q < wave; ++q) base += wsum[q];
  if (i < nblk) bsum[i] = base + inc - v;
  if (i == 0) row_ptr[n] = m;
}

__global__ __launch_bounds__(256) void scanC_k(const int* __restrict__ counts,
                                               const int* __restrict__ bsum,
                                               int* __restrict__ row_ptr,
                                               int* __restrict__ cursor, int n) {
  const int i = blockIdx.x * 256 + threadIdx.x;
  const int lane = threadIdx.x & 63;
  const int wave = threadIdx.x >> 6;
  const int v = (i < n) ? counts[i] : 0;
  int inc = v;
#pragma unroll
  for (int d = 1; d < 64; d <<= 1) {
    int t = __shfl_up(inc, d);
    if (lane >= d) inc += t;
  }
  __shared__ int wsum[4];
  if (lane == 63) wsum[wave] = inc;
  __syncthreads();
  int base = bsum[blockIdx.x];
  for (int q = 0; q < wave; ++q) base += wsum[q];
  const int excl = base + inc - v;
  if (i < n) { row_ptr[i] = excl; cursor[i] = excl; }
}

__global__ __launch_bounds__(256) void scatter_k(const int* __restrict__ src,
                                                 const int* __restrict__ trg,
                                                 int* __restrict__ cursor,
                                                 int* __restrict__ src_sorted, int m) {
  const int e = blockIdx.x * blockDim.x + threadIdx.x;
  if (e < m) {
    const int pos = atomicAdd(&cursor[trg[e]], 1);
    src_sorted[pos] = src[e];
  }
}

// ---------------------------------------------------------------------------
// One FULL routing layer (3 iterations fused), wave-per-node, 16 lanes/edge.
// u in registers across iterations; z gathered once (t=0), first CAP edges
// cached in per-wave LDS; overflow re-gathered. Softmax denominator reduce is
// ALL-VALU DPP: xor2 + row_ror:4 + row_ror:8 covers each of the 8 capsules
// exactly once. Zero DS ops per edge.
// MODE 1: dst = capsnorm(lrelu(u3))   (layer boundary)
// MODE 2: dst = lrelu(u3)             (final output)
// ---------------------------------------------------------------------------
template <int MODE>
__global__ __launch_bounds__(256) void rout_layer_k(
    const int* __restrict__ row_ptr, const int* __restrict__ src_sorted,
    const float* __restrict__ xn, float* __restrict__ dst, int n) {
  __shared__ float zc[4][CAP * 64];
  const int wv   = threadIdx.x >> 6;
  const int wid  = blockIdx.x * 4 + wv;
  const int lane = threadIdx.x & 63;
  if (wid >= n) return;
  const int g = lane >> 4;          // edge slot 0..3
  const int q = lane & 15;          // float4 chunk (dims 4q..4q+3)
  const size_t rowj = (size_t)wid * 64 + q * 4;
  float* zbase = &zc[wv][0];

  const float4 xj = *reinterpret_cast<const float4*>(xn + rowj);
  float u0 = xj.x, u1 = xj.y, u2 = xj.z, u3 = xj.w;   // u = x initially

  const int e0  = row_ptr[wid];
  const int end = row_ptr[wid + 1];
  const int ntile = (end - e0 + 3) >> 2;

  for (int t = 0; t < 3; ++t) {
    float a0 = 0.f, a1 = 0.f, a2 = 0.f, a3 = 0.f;

#define EDGE_BODY(Z)                                                   \
    {                                                                  \
      float d = (Z).x * u0;                                            \
      d = fmaf((Z).y, u1, d);                                          \
      d = fmaf((Z).z, u2, d);                                          \
      d = fmaf((Z).w, u3, d);                                          \
      d = dpp_add<0xB1>(d);              /* 8-dim capsule dot */       \
      const float ee = __expf(d);        /* |d|<=1: unit capsules */   \
      float sm = dpp_add<0x4E>(ee);      /* + capsule c^1        */    \
      sm = dpp_add<0x124>(sm);           /* + ror4               */    \
      sm = dpp_add<0x128>(sm);           /* + ror8: all 8 caps   */    \
      const float wgt = ee * __builtin_amdgcn_rcpf(sm);                \
      a0 = fmaf((Z).x, wgt, a0);                                       \
      a1 = fmaf((Z).y, wgt, a1);                                       \
      a2 = fmaf((Z).z, wgt, a2);                                       \
      a3 = fmaf((Z).w, wgt, a3);                                       \
    }

    if (t == 0) {
      int e = e0 + g;
      bool vn = e < end;
      int  sn = vn ? src_sorted[e] : wid;
      float4 zn = *reinterpret_cast<const float4*>(xn + (size_t)sn * 64 + q * 4);
      if (!vn) zn = make_float4(0.f, 0.f, 0.f, 0.f);
      for (int it = 0; it < ntile; ++it) {
        const float4 z = zn;
        e += 4;
        const bool v2 = e < end;
        const int  s2 = v2 ? src_sorted[e] : wid;
        float4 tz = *reinterpret_cast<const float4*>(xn + (size_t)s2 * 64 + q * 4);
        zn = v2 ? tz : make_float4(0.f, 0.f, 0.f, 0.f);
        const int slot = it * 4 + g;
        if (slot < CAP)
          *reinterpret_cast<float4*>(zbase + slot * 64 + q * 4) = z;
        EDGE_BODY(z)
      }
    } else {
      for (int it = 0; it < ntile; ++it) {
        const int slot = it * 4 + g;
        float4 z;
        if (slot < CAP) {
          z = *reinterpret_cast<const float4*>(zbase + slot * 64 + q * 4);
        } else {
          const int e = e0 + slot;
          const bool vv = e < end;
          const int ss = vv ? src_sorted[e] : wid;
          z = *reinterpret_cast<const float4*>(xn + (size_t)ss * 64 + q * 4);
          if (!vv) z = make_float4(0.f, 0.f, 0.f, 0.f);
        }
        EDGE_BODY(z)
      }
    }
#undef EDGE_BODY

    // combine the 4 edge slots (lane bits 4,5)
    a0 += __shfl_xor(a0, 16); a0 += __shfl_xor(a0, 32);
    a1 += __shfl_xor(a1, 16); a1 += __shfl_xor(a1, 32);
    a2 += __shfl_xor(a2, 16); a2 += __shfl_xor(a2, 32);
    a3 += __shfl_xor(a3, 16); a3 += __shfl_xor(a3, 32);
    // + x, capsnorm -> next u
    a0 += xj.x; a1 += xj.y; a2 += xj.z; a3 += xj.w;
    float ss = a0 * a0 + a1 * a1 + a2 * a2 + a3 * a3;
    ss = dpp_add<0xB1>(ss);
    const float inv = 1.0f / fmaxf(sqrtf(ss), EPSN);
    u0 = a0 * inv; u1 = a1 * inv; u2 = a2 * inv; u3 = a3 * inv;
  }

  // boundary transforms
  float v0 = u0, v1 = u1, v2 = u2, v3 = u3;
  v0 = v0 > 0.f ? v0 : SLOPE * v0;
  v1 = v1 > 0.f ? v1 : SLOPE * v1;
  v2 = v2 > 0.f ? v2 : SLOPE * v2;
  v3 = v3 > 0.f ? v3 : SLOPE * v3;
  if (MODE == 1) {   // re-capsnorm for next layer's x
    float s3 = v0 * v0 + v1 * v1 + v2 * v2 + v3 * v3;
    s3 = dpp_add<0xB1>(s3);
    const float inv3 = 1.0f / fmaxf(sqrtf(s3), EPSN);
    v0 *= inv3; v1 *= inv3; v2 *= inv3; v3 *= inv3;
  }
  if (g == 0) {
    *reinterpret_cast<float4*>(dst + rowj) = make_float4(v0, v1, v2, v3);
  }
}

// ---------------------------------------------------------------------------
extern "C" void kernel_launch(void* const* d_in, const int* in_sizes, int n_in,
                              void* d_out, int out_size, void* d_ws, size_t ws_size,
                              hipStream_t stream) {
  const float* x       = (const float*)d_in[0];
  const int*   src_trg = (const int*)d_in[1];
  const float* W       = (const float*)d_in[2];
  const float* b       = (const float*)d_in[3];

  const int hid    = in_sizes[3];          // 64
  const int in_dim = in_sizes[2] / hid;    // 500
  const int n      = in_sizes[0] / in_dim; // 50000
  const int m      = in_sizes[1] / 2;      // 500000
  const int* src = src_trg;
  const int* trg = src_trg + m;

  const size_t n64 = (size_t)n * hid;      // 3.2M floats
  float* xn_a = (float*)d_ws;              // layer-1 normalized features
  float* xn_b = xn_a + n64;                // layer-2 normalized features
  short* w2h  = (short*)(xn_b + n64);      // KPAD*64 bf16 hi (swizzled)
  short* w2l  = w2h + KPAD * 64;           // KPAD*64 bf16 lo
  int*   ip   = (int*)(w2l + KPAD * 64);
  int* counts     = ip;                    // n
  int* row_ptr    = counts + n;            // n+1
  int* cursor     = row_ptr + n + 1;       // n
  int* bsum       = cursor + n;            // nblk
  const int nblk  = (n + 255) / 256;       // 196 (<= 256 required by scanB)
  int* src_sorted = bsum + nblk;           // m
  float* out = (float*)d_out;

  const int mg = (m + 255) / 256;

  // --- CSR build (once per call) ---
  zero_int_k<<<nblk, 256, 0, stream>>>(counts, n);
  hist_k<<<mg, 256, 0, stream>>>(trg, counts, m);
  scanA_k<<<nblk, 256, 0, stream>>>(counts, bsum, n);
  scanB_k<<<1, 256, 0, stream>>>(bsum, nblk, row_ptr, n, m);
  scanC_k<<<nblk, 256, 0, stream>>>(counts, bsum, row_ptr, cursor, n);
  scatter_k<<<mg, 256, 0, stream>>>(src, trg, cursor, src_sorted, m);

  // --- W prep + fused MFMA GEMM: xn_a = capsnorm(lrelu(x @ W + b)) ---
  prep_w_k<<<(KPAD * 64) / 256, 256, 0, stream>>>(W, w2h, w2l, in_dim);
  gemm_mfma_capsnorm_k<<<(n + 63) / 64, 256, 0, stream>>>(
      x, w2h, w2l, b, xn_a, n, in_dim);

  // --- routing: one fused kernel per layer (3 iterations each) ---
  const int rb = (n + 3) / 4;  // 4 waves (nodes) per 256-thread block
  rout_layer_k<1><<<rb, 256, 0, stream>>>(row_ptr, src_sorted, xn_a, xn_b, n);
  rout_layer_k<2><<<rb, 256, 0, stream>>>(row_ptr, src_sorted, xn_b, out, n);
}

// Round 9
// 169.807 us; speedup vs baseline: 1.1429x; 1.1429x over previous
//
#include <hip/hip_runtime.h>
#include <hip/hip_bf16.h>

static constexpr float SLOPE = 0.01f;   // leaky_relu negative_slope
static constexpr float EPSN  = 1e-12f;  // F.normalize eps

typedef float f32x4 __attribute__((ext_vector_type(4)));
typedef short short8 __attribute__((ext_vector_type(8)));

#define KPAD 512     // in_dim = 500 padded to 16 k-steps of 32 (8 tiles of 64)
#define CAP  16      // edges per node cached in LDS for routing iters 2,3

// VALU (DPP) butterfly/rotate add: x + dpp(x). No DS-pipe traffic.
template <int CTRL>
__device__ __forceinline__ float dpp_add(float x) {
  const int y = __builtin_amdgcn_mov_dpp(__builtin_bit_cast(int, x), CTRL, 0xF, 0xF, true);
  return x + __builtin_bit_cast(float, y);
}

// round-to-nearest bf16 split: v ~= hi + lo, each exactly representable in bf16
__device__ __forceinline__ void bf16_split(float v, short& hi, short& lo) {
  __hip_bfloat16 h = __float2bfloat16(v);
  float hf = __bfloat162float(h);
  __hip_bfloat16 l = __float2bfloat16(v - hf);
  hi = __builtin_bit_cast(short, h);
  lo = __builtin_bit_cast(short, l);
}

// async global->LDS DMA, 16B per lane. LDS dest = base + lane*16 (linear).
__device__ __forceinline__ void load_lds16(const float* g, float* l) {
  __builtin_amdgcn_global_load_lds(
      (const __attribute__((address_space(1))) unsigned int*)g,
      (__attribute__((address_space(3))) unsigned int*)l, 16, 0, 0);
}

// ---------------------------------------------------------------------------
// One-time W prep: split to bf16 hi/lo, swizzle to w2[kstep][kc][col][8],
// zero-pad k to KPAD. Also zeroes the 16B zbuf used for A-tail redirect.
// ---------------------------------------------------------------------------
__global__ __launch_bounds__(256) void prep_w_k(const float* __restrict__ W,
                                                short* __restrict__ w2h,
                                                short* __restrict__ w2l,
                                                float* __restrict__ zbuf, int in_dim) {
  const int idx = blockIdx.x * 256 + threadIdx.x;   // over KPAD*64
  if (idx < 4) zbuf[idx] = 0.0f;
  if (idx >= KPAD * 64) return;
  const int k = idx >> 6, col = idx & 63;
  const float v = (k < in_dim) ? W[(size_t)k * 64 + col] : 0.0f;
  short hi, lo;
  bf16_split(v, hi, lo);
  const int kt = k >> 5, kc = (k >> 3) & 3, e = k & 7;
  const int off = (((kt * 4 + kc) * 64) + col) * 8 + e;
  w2h[off] = hi;
  w2l[off] = lo;
}

// ---------------------------------------------------------------------------
// Stage one 16-row x 64-float A tile via 4 async DMA calls (1KB each).
// LDS layout (per wave, per buffer): [row 0..15][granule slot 0..15][4 floats],
// where slot sl of row r holds global granule sl ^ (r&7)  (XOR bank swizzle,
// applied on the per-lane GLOBAL address: both-sides rule).
// Rows >= n clamp to n-1 (garbage rows never stored); granules past
// in_dim (in_dim%4==0 -> no partial granules) redirect to the 16B zero buf.
// ---------------------------------------------------------------------------
__device__ __forceinline__ void stage_tile(const float* __restrict__ x,
                                           const float* __restrict__ zbuf,
                                           float* ldsbuf, int row0w, int kt,
                                           int n, int in_dim, int lane) {
  const int rl = lane >> 4;          // row within 4-row call group
  const int gl = lane & 15;          // destination granule slot
#pragma unroll
  for (int i = 0; i < 4; ++i) {
    const int r    = i * 4 + rl;
    const int gsrc = gl ^ (r & 7);
    const int k    = kt * 64 + gsrc * 4;
    int grow = row0w + r;
    grow = grow < n ? grow : n - 1;
    const float* src = (k + 4 <= in_dim) ? (x + (size_t)grow * in_dim + k) : zbuf;
    load_lds16(src, ldsbuf + i * 256);   // 4 rows * 64 floats per call
  }
}

// ---------------------------------------------------------------------------
// Fused MFMA GEMM: xn = capsnorm(leaky_relu(x @ W + b)).
// 64 rows/block, 4 waves x 16 rows, per-wave-PRIVATE double-buffered A tiles
// staged with global_load_lds (async DMA; no barriers, no VGPR round-trip).
// Per tile: ds_read cur fragments -> issue DMA for next tile -> split+MFMA
// (next tile's loads fly under the compute). B fragments from pre-swizzled
// w2h/w2l in global (L2-resident). Split-bf16: acc += Ah*Bh + Ah*Bl + Al*Bh.
// C/D: col=lane&15, row=(lane>>4)*4+reg (verified m89).
// ---------------------------------------------------------------------------
__global__ __launch_bounds__(256) void gemm_mfma_capsnorm_k(
    const float* __restrict__ x, const short* __restrict__ w2h,
    const short* __restrict__ w2l, const float* __restrict__ b,
    const float* __restrict__ zbuf, float* __restrict__ xn, int n, int in_dim) {
  __shared__ __align__(16) float xs[4][2][1024];   // [wave][buf][16 rows x 64 f] = 32KB

  const int tid   = threadIdx.x;
  const int lane  = tid & 63;
  const int w     = tid >> 6;
  const int l15   = lane & 15;
  const int kcL   = lane >> 4;
  const int row0  = blockIdx.x * 64;
  const int row0w = row0 + w * 16;
  const int sw4   = l15 & 7;

  f32x4 acc0 = {0.f, 0.f, 0.f, 0.f};
  f32x4 acc1 = {0.f, 0.f, 0.f, 0.f};
  f32x4 acc2 = {0.f, 0.f, 0.f, 0.f};
  f32x4 acc3 = {0.f, 0.f, 0.f, 0.f};

  // prologue: stage tile 0
  stage_tile(x, zbuf, &xs[w][0][0], row0w, 0, n, in_dim, lane);

  for (int kt = 0; kt < 8; ++kt) {
    float* cur = &xs[w][kt & 1][0];
    float* nxt = &xs[w][(kt & 1) ^ 1][0];

    // fragments for both k-steps of this tile (compiler waits cur's 4 DMAs)
    const int s00 = ((kcL * 2)     ^ sw4) * 4;
    const int s01 = ((kcL * 2 + 1) ^ sw4) * 4;
    const int s10 = ((8 + kcL * 2)     ^ sw4) * 4;
    const int s11 = ((8 + kcL * 2 + 1) ^ sw4) * 4;
    const float4 fa0 = *reinterpret_cast<const float4*>(&cur[l15 * 64 + s00]);
    const float4 fb0 = *reinterpret_cast<const float4*>(&cur[l15 * 64 + s01]);
    const float4 fa1 = *reinterpret_cast<const float4*>(&cur[l15 * 64 + s10]);
    const float4 fb1 = *reinterpret_cast<const float4*>(&cur[l15 * 64 + s11]);

    // prefetch next tile: DMA flies under the split+B-load+MFMA phase below
    if (kt < 7) stage_tile(x, zbuf, nxt, row0w, kt + 1, n, in_dim, lane);

#pragma unroll
    for (int ks = 0; ks < 2; ++ks) {
      const float4 A0 = ks ? fa1 : fa0;
      const float4 A1 = ks ? fb1 : fb0;
      short hb[8], lb[8];
      bf16_split(A0.x, hb[0], lb[0]);
      bf16_split(A0.y, hb[1], lb[1]);
      bf16_split(A0.z, hb[2], lb[2]);
      bf16_split(A0.w, hb[3], lb[3]);
      bf16_split(A1.x, hb[4], lb[4]);
      bf16_split(A1.y, hb[5], lb[5]);
      bf16_split(A1.z, hb[6], lb[6]);
      bf16_split(A1.w, hb[7], lb[7]);
      const short8 ah = *reinterpret_cast<const short8*>(hb);
      const short8 al = *reinterpret_cast<const short8*>(lb);
      const int ktg = kt * 2 + ks;
      const size_t base = ((size_t)(ktg * 4 + kcL) * 64) * 8;
#pragma unroll
      for (int nt = 0; nt < 4; ++nt) {
        const short8 bh = *reinterpret_cast<const short8*>(w2h + base + (size_t)(nt * 16 + l15) * 8);
        const short8 bl = *reinterpret_cast<const short8*>(w2l + base + (size_t)(nt * 16 + l15) * 8);
        f32x4& acc = nt == 0 ? acc0 : nt == 1 ? acc1 : nt == 2 ? acc2 : acc3;
        acc = __builtin_amdgcn_mfma_f32_16x16x32_bf16(ah, bh, acc, 0, 0, 0);
        acc = __builtin_amdgcn_mfma_f32_16x16x32_bf16(ah, bl, acc, 0, 0, 0);
        acc = __builtin_amdgcn_mfma_f32_16x16x32_bf16(al, bh, acc, 0, 0, 0);
      }
    }
  }

  // --- epilogue: bias + leaky_relu + capsnorm (capsule = 8 cols) ---
#pragma unroll
  for (int nt = 0; nt < 4; ++nt) {
    const f32x4 acc = nt == 0 ? acc0 : nt == 1 ? acc1 : nt == 2 ? acc2 : acc3;
    const float bcol = b[nt * 16 + l15];
#pragma unroll
    for (int reg = 0; reg < 4; ++reg) {
      float v = acc[reg] + bcol;
      v = v > 0.f ? v : SLOPE * v;
      float s = v * v;
      s = dpp_add<0xB1>(s);        // xor1 (VALU)
      s = dpp_add<0x4E>(s);        // xor2 (VALU)
      s += __shfl_xor(s, 4);       // xor4
      const float inv = 1.0f / fmaxf(sqrtf(s), EPSN);
      const int grow = row0 + w * 16 + ((lane >> 4) << 2) + reg;
      if (grow < n) xn[(size_t)grow * 64 + nt * 16 + l15] = v * inv;
    }
  }
}

// ---------------------------------------------------------------------------
// CSR construction: counts -> exclusive scan -> cursor scatter
// ---------------------------------------------------------------------------
__global__ __launch_bounds__(256) void zero_int_k(int* __restrict__ p, int n) {
  const int i = blockIdx.x * blockDim.x + threadIdx.x;
  if (i < n) p[i] = 0;
}

__global__ __launch_bounds__(256) void hist_k(const int* __restrict__ trg,
                                              int* __restrict__ counts, int m) {
  const int e = blockIdx.x * blockDim.x + threadIdx.x;
  if (e < m) atomicAdd(&counts[trg[e]], 1);
}

__global__ __launch_bounds__(256) void scanA_k(const int* __restrict__ counts,
                                               int* __restrict__ bsum, int n) {
  const int i = blockIdx.x * 256 + threadIdx.x;
  int v = (i < n) ? counts[i] : 0;
  v += __shfl_xor(v, 1);  v += __shfl_xor(v, 2);  v += __shfl_xor(v, 4);
  v += __shfl_xor(v, 8);  v += __shfl_xor(v, 16); v += __shfl_xor(v, 32);
  __shared__ int wsum[4];
  if ((threadIdx.x & 63) == 0) wsum[threadIdx.x >> 6] = v;
  __syncthreads();
  if (threadIdx.x == 0) bsum[blockIdx.x] = wsum[0] + wsum[1] + wsum[2] + wsum[3];
}

// PARALLEL exclusive scan of block sums (nblk <= 256)
__global__ __launch_bounds__(256) void scanB_k(int* __restrict__ bsum, int nblk,
                                               int* __restrict__ row_ptr, int n, int m) {
  const int i = threadIdx.x;
  const int lane = i & 63;
  const int wave = i >> 6;
  const int v = (i < nblk) ? bsum[i] : 0;
  int inc = v;
#pragma unroll
  for (int d = 1; d < 64; d <<= 1) {
    int t = __shfl_up(inc, d);
    if (lane >= d) inc += t;
  }
  __shared__ int wsum[4];
  if (lane == 63) wsum[wave] = inc;
  __syncthreads();
  int base = 0;
  for (int q = 0; q < wave; ++q) base += wsum[q];
  if (i < nblk) bsum[i] = base + inc - v;
  if (i == 0) row_ptr[n] = m;
}

__global__ __launch_bounds__(256) void scanC_k(const int* __restrict__ counts,
                                               const int* __restrict__ bsum,
                                               int* __restrict__ row_ptr,
                                               int* __restrict__ cursor, int n) {
  const int i = blockIdx.x * 256 + threadIdx.x;
  const int lane = threadIdx.x & 63;
  const int wave = threadIdx.x >> 6;
  const int v = (i < n) ? counts[i] : 0;
  int inc = v;
#pragma unroll
  for (int d = 1; d < 64; d <<= 1) {
    int t = __shfl_up(inc, d);
    if (lane >= d) inc += t;
  }
  __shared__ int wsum[4];
  if (lane == 63) wsum[wave] = inc;
  __syncthreads();
  int base = bsum[blockIdx.x];
  for (int q = 0; q < wave; ++q) base += wsum[q];
  const int excl = base + inc - v;
  if (i < n) { row_ptr[i] = excl; cursor[i] = excl; }
}

__global__ __launch_bounds__(256) void scatter_k(const int* __restrict__ src,
                                                 const int* __restrict__ trg,
                                                 int* __restrict__ cursor,
                                                 int* __restrict__ src_sorted, int m) {
  const int e = blockIdx.x * blockDim.x + threadIdx.x;
  if (e < m) {
    const int pos = atomicAdd(&cursor[trg[e]], 1);
    src_sorted[pos] = src[e];
  }
}

// ---------------------------------------------------------------------------
// One FULL routing layer (3 iterations fused), wave-per-node, 16 lanes/edge.
// u in registers across iterations; z gathered once (t=0), first CAP edges
// cached in per-wave LDS; overflow re-gathered. Softmax denominator reduce is
// ALL-VALU DPP: xor2 + row_ror:4 + row_ror:8 covers each of the 8 capsules
// exactly once. Zero DS ops per edge.
// MODE 1: dst = capsnorm(lrelu(u3))   (layer boundary)
// MODE 2: dst = lrelu(u3)             (final output)
// ---------------------------------------------------------------------------
template <int MODE>
__global__ __launch_bounds__(256) void rout_layer_k(
    const int* __restrict__ row_ptr, const int* __restrict__ src_sorted,
    const float* __restrict__ xn, float* __restrict__ dst, int n) {
  __shared__ float zc[4][CAP * 64];
  const int wv   = threadIdx.x >> 6;
  const int wid  = blockIdx.x * 4 + wv;
  const int lane = threadIdx.x & 63;
  if (wid >= n) return;
  const int g = lane >> 4;          // edge slot 0..3
  const int q = lane & 15;          // float4 chunk (dims 4q..4q+3)
  const size_t rowj = (size_t)wid * 64 + q * 4;
  float* zbase = &zc[wv][0];

  const float4 xj = *reinterpret_cast<const float4*>(xn + rowj);
  float u0 = xj.x, u1 = xj.y, u2 = xj.z, u3 = xj.w;   // u = x initially

  const int e0  = row_ptr[wid];
  const int end = row_ptr[wid + 1];
  const int ntile = (end - e0 + 3) >> 2;

  for (int t = 0; t < 3; ++t) {
    float a0 = 0.f, a1 = 0.f, a2 = 0.f, a3 = 0.f;

#define EDGE_BODY(Z)                                                   \
    {                                                                  \
      float d = (Z).x * u0;                                            \
      d = fmaf((Z).y, u1, d);                                          \
      d = fmaf((Z).z, u2, d);                                          \
      d = fmaf((Z).w, u3, d);                                          \
      d = dpp_add<0xB1>(d);              /* 8-dim capsule dot */       \
      const float ee = __expf(d);        /* |d|<=1: unit capsules */   \
      float sm = dpp_add<0x4E>(ee);      /* + capsule c^1        */    \
      sm = dpp_add<0x124>(sm);           /* + ror4               */    \
      sm = dpp_add<0x128>(sm);           /* + ror8: all 8 caps   */    \
      const float wgt = ee * __builtin_amdgcn_rcpf(sm);                \
      a0 = fmaf((Z).x, wgt, a0);                                       \
      a1 = fmaf((Z).y, wgt, a1);                                       \
      a2 = fmaf((Z).z, wgt, a2);                                       \
      a3 = fmaf((Z).w, wgt, a3);                                       \
    }

    if (t == 0) {
      int e = e0 + g;
      bool vn = e < end;
      int  sn = vn ? src_sorted[e] : wid;
      float4 zn = *reinterpret_cast<const float4*>(xn + (size_t)sn * 64 + q * 4);
      if (!vn) zn = make_float4(0.f, 0.f, 0.f, 0.f);
      for (int it = 0; it < ntile; ++it) {
        const float4 z = zn;
        e += 4;
        const bool v2 = e < end;
        const int  s2 = v2 ? src_sorted[e] : wid;
        float4 tz = *reinterpret_cast<const float4*>(xn + (size_t)s2 * 64 + q * 4);
        zn = v2 ? tz : make_float4(0.f, 0.f, 0.f, 0.f);
        const int slot = it * 4 + g;
        if (slot < CAP)
          *reinterpret_cast<float4*>(zbase + slot * 64 + q * 4) = z;
        EDGE_BODY(z)
      }
    } else {
      for (int it = 0; it < ntile; ++it) {
        const int slot = it * 4 + g;
        float4 z;
        if (slot < CAP) {
          z = *reinterpret_cast<const float4*>(zbase + slot * 64 + q * 4);
        } else {
          const int e = e0 + slot;
          const bool vv = e < end;
          const int ss = vv ? src_sorted[e] : wid;
          z = *reinterpret_cast<const float4*>(xn + (size_t)ss * 64 + q * 4);
          if (!vv) z = make_float4(0.f, 0.f, 0.f, 0.f);
        }
        EDGE_BODY(z)
      }
    }
#undef EDGE_BODY

    // combine the 4 edge slots (lane bits 4,5)
    a0 += __shfl_xor(a0, 16); a0 += __shfl_xor(a0, 32);
    a1 += __shfl_xor(a1, 16); a1 += __shfl_xor(a1, 32);
    a2 += __shfl_xor(a2, 16); a2 += __shfl_xor(a2, 32);
    a3 += __shfl_xor(a3, 16); a3 += __shfl_xor(a3, 32);
    // + x, capsnorm -> next u
    a0 += xj.x; a1 += xj.y; a2 += xj.z; a3 += xj.w;
    float ss = a0 * a0 + a1 * a1 + a2 * a2 + a3 * a3;
    ss = dpp_add<0xB1>(ss);
    const float inv = 1.0f / fmaxf(sqrtf(ss), EPSN);
    u0 = a0 * inv; u1 = a1 * inv; u2 = a2 * inv; u3 = a3 * inv;
  }

  // boundary transforms
  float v0 = u0, v1 = u1, v2 = u2, v3 = u3;
  v0 = v0 > 0.f ? v0 : SLOPE * v0;
  v1 = v1 > 0.f ? v1 : SLOPE * v1;
  v2 = v2 > 0.f ? v2 : SLOPE * v2;
  v3 = v3 > 0.f ? v3 : SLOPE * v3;
  if (MODE == 1) {   // re-capsnorm for next layer's x
    float s3 = v0 * v0 + v1 * v1 + v2 * v2 + v3 * v3;
    s3 = dpp_add<0xB1>(s3);
    const float inv3 = 1.0f / fmaxf(sqrtf(s3), EPSN);
    v0 *= inv3; v1 *= inv3; v2 *= inv3; v3 *= inv3;
  }
  if (g == 0) {
    *reinterpret_cast<float4*>(dst + rowj) = make_float4(v0, v1, v2, v3);
  }
}

// ---------------------------------------------------------------------------
extern "C" void kernel_launch(void* const* d_in, const int* in_sizes, int n_in,
                              void* d_out, int out_size, void* d_ws, size_t ws_size,
                              hipStream_t stream) {
  const float* x       = (const float*)d_in[0];
  const int*   src_trg = (const int*)d_in[1];
  const float* W       = (const float*)d_in[2];
  const float* b       = (const float*)d_in[3];

  const int hid    = in_sizes[3];          // 64
  const int in_dim = in_sizes[2] / hid;    // 500
  const int n      = in_sizes[0] / in_dim; // 50000
  const int m      = in_sizes[1] / 2;      // 500000
  const int* src = src_trg;
  const int* trg = src_trg + m;

  const size_t n64 = (size_t)n * hid;      // 3.2M floats
  float* xn_a = (float*)d_ws;              // layer-1 normalized features
  float* xn_b = xn_a + n64;                // layer-2 normalized features
  short* w2h  = (short*)(xn_b + n64);      // KPAD*64 bf16 hi (swizzled)
  short* w2l  = w2h + KPAD * 64;           // KPAD*64 bf16 lo
  float* zbuf = (float*)(w2l + KPAD * 64); // 16B zero granule (A-tail redirect)
  int*   ip   = (int*)(zbuf + 4);
  int* counts     = ip;                    // n
  int* row_ptr    = counts + n;            // n+1
  int* cursor     = row_ptr + n + 1;       // n
  int* bsum       = cursor + n;            // nblk
  const int nblk  = (n + 255) / 256;       // 196 (<= 256 required by scanB)
  int* src_sorted = bsum + nblk;           // m
  float* out = (float*)d_out;

  const int mg = (m + 255) / 256;

  // --- CSR build (once per call) ---
  zero_int_k<<<nblk, 256, 0, stream>>>(counts, n);
  hist_k<<<mg, 256, 0, stream>>>(trg, counts, m);
  scanA_k<<<nblk, 256, 0, stream>>>(counts, bsum, n);
  scanB_k<<<1, 256, 0, stream>>>(bsum, nblk, row_ptr, n, m);
  scanC_k<<<nblk, 256, 0, stream>>>(counts, bsum, row_ptr, cursor, n);
  scatter_k<<<mg, 256, 0, stream>>>(src, trg, cursor, src_sorted, m);

  // --- W prep + fused MFMA GEMM: xn_a = capsnorm(lrelu(x @ W + b)) ---
  prep_w_k<<<(KPAD * 64) / 256, 256, 0, stream>>>(W, w2h, w2l, zbuf, in_dim);
  gemm_mfma_capsnorm_k<<<(n + 63) / 64, 256, 0, stream>>>(
      x, w2h, w2l, b, zbuf, xn_a, n, in_dim);

  // --- routing: one fused kernel per layer (3 iterations each) ---
  const int rb = (n + 3) / 4;  // 4 waves (nodes) per 256-thread block
  rout_layer_k<1><<<rb, 256, 0, stream>>>(row_ptr, src_sorted, xn_a, xn_b, n);
  rout_layer_k<2><<<rb, 256, 0, stream>>>(row_ptr, src_sorted, xn_b, out, n);
}